// Round 1
// baseline (228.489 us; speedup 1.0000x reference)
//
#include <hip/hip_runtime.h>
#include <hip/hip_bf16.h>

typedef short short8 __attribute__((ext_vector_type(8)));
typedef float floatx4 __attribute__((ext_vector_type(4)));

#define S_LEN 2048
#define DMODEL 1024
#define NH 16
#define HD 64
#define BATCH 2

static __device__ __forceinline__ short f2bf(float x) {
    __hip_bfloat16 h = __float2bfloat16(x);
    return *(short*)&h;
}

// async 16B global->LDS (wave-uniform LDS base + lane*16 contract)
static __device__ __forceinline__ void async_ld16(const __hip_bfloat16* g, __hip_bfloat16* l) {
    __builtin_amdgcn_global_load_lds(
        (const __attribute__((address_space(1))) unsigned int*)g,
        (__attribute__((address_space(3))) unsigned int*)l, 16, 0, 0);
}

// ---------------- fp32 -> bf16 bulk convert ----------------
__global__ __launch_bounds__(256) void cvt_kernel(const float* __restrict__ X,
                                                  __hip_bfloat16* __restrict__ Y) {
    int i = (blockIdx.x * 256 + threadIdx.x) * 8;
    floatx4 f0 = *(const floatx4*)&X[i];
    floatx4 f1 = *(const floatx4*)&X[i + 4];
    short8 s;
    s[0] = f2bf(f0[0]); s[1] = f2bf(f0[1]); s[2] = f2bf(f0[2]); s[3] = f2bf(f0[3]);
    s[4] = f2bf(f1[0]); s[5] = f2bf(f1[1]); s[6] = f2bf(f1[2]); s[7] = f2bf(f1[3]);
    *(short8*)&Y[i] = s;
}

// ---------------- weight transpose + downcast: Wt[N][K] = bf16(W[K][N]) ----------------
__global__ void transpose_kernel(const float* __restrict__ W,
                                 __hip_bfloat16* __restrict__ Wt, int K, int N) {
    __shared__ float tile[32][33];
    int n0 = blockIdx.x * 32, k0 = blockIdx.y * 32;
    int tx = threadIdx.x, ty = threadIdx.y;  // blockDim = (32,8)
#pragma unroll
    for (int i = 0; i < 32; i += 8)
        tile[ty + i][tx] = W[(size_t)(k0 + ty + i) * N + n0 + tx];
    __syncthreads();
#pragma unroll
    for (int i = 0; i < 32; i += 8)
        Wt[(size_t)(n0 + ty + i) * K + k0 + tx] = __float2bfloat16(tile[tx][ty + i]);
}

// ---------------- MFMA GEMM v2: 128x128 tile, BK=32, global_load_lds (unchanged) ----------------
__global__ __launch_bounds__(256) void gemm128(
    const __hip_bfloat16* __restrict__ A, const __hip_bfloat16* __restrict__ Bt,
    const float* __restrict__ bias, float* __restrict__ Cf,
    __hip_bfloat16* __restrict__ Qp, __hip_bfloat16* __restrict__ Kp,
    __hip_bfloat16* __restrict__ Vt, int M, int N, int K, int mode) {
    __shared__ __align__(16) __hip_bfloat16 As[128 * 32];
    __shared__ __align__(16) __hip_bfloat16 Bs[128 * 32];
    const int m0 = blockIdx.y * 128, n0 = blockIdx.x * 128;
    const int t = threadIdx.x;
    const int wave = t >> 6, lane = t & 63;
    const int quad = lane >> 4, m16 = lane & 15;
    const int wm = (wave >> 1) * 64, wn = (wave & 1) * 64;
    const int srow = lane >> 2, scol = (lane & 3) * 8;

    floatx4 acc[4][4] = {};
    for (int k0 = 0; k0 < K; k0 += 32) {
#pragma unroll
        for (int i = 0; i < 2; i++) {
            const int rbase = wave * 32 + i * 16;
            async_ld16(&A[(size_t)(m0 + rbase + srow) * K + k0 + scol], &As[rbase * 32]);
            async_ld16(&Bt[(size_t)(n0 + rbase + srow) * K + k0 + scol], &Bs[rbase * 32]);
        }
        __syncthreads();
        short8 af[4], bfr[4];
#pragma unroll
        for (int i = 0; i < 4; i++)
            af[i] = *(const short8*)&As[(wm + i * 16 + m16) * 32 + quad * 8];
#pragma unroll
        for (int j = 0; j < 4; j++)
            bfr[j] = *(const short8*)&Bs[(wn + j * 16 + m16) * 32 + quad * 8];
#pragma unroll
        for (int i = 0; i < 4; i++)
#pragma unroll
            for (int j = 0; j < 4; j++)
                acc[i][j] = __builtin_amdgcn_mfma_f32_16x16x32_bf16(af[i], bfr[j], acc[i][j], 0, 0, 0);
        __syncthreads();
    }
#pragma unroll
    for (int i = 0; i < 4; i++)
#pragma unroll
        for (int j = 0; j < 4; j++) {
            int col = n0 + wn + j * 16 + m16;
            float bv = bias[col];
#pragma unroll
            for (int r = 0; r < 4; r++) {
                int row = m0 + wm + i * 16 + quad * 4 + r;
                float v = acc[i][j][r] + bv;
                if (mode == 0) {
                    Cf[(size_t)row * N + col] = v;
                } else {
                    __hip_bfloat16 hv = __float2bfloat16(v);
                    int tt = col >> 10, rem = col & 1023;
                    int h = rem >> 6, d = rem & 63;
                    int b = row >> 11, s = row & 2047;
                    if (tt == 0)      Qp[((size_t)(b * NH + h) * S_LEN + s) * HD + d] = hv;
                    else if (tt == 1) Kp[((size_t)(b * NH + h) * S_LEN + s) * HD + d] = hv;
                    else              Vt[((size_t)(b * NH + h) * HD + d) * S_LEN + s] = hv;
                }
            }
        }
}

// ---------------- MFMA flash attention v5 ----------------
// grid (B*H, S/64), block 256 (4 waves); each wave owns a 16-query tile.
// K/V tiles staged via global_load_lds (packed rows; swizzled SOURCE addresses so
// fragment reads are bank-conflict-free). Fixed-max softmax, Ps wave-private.
// v5 changes vs v4 (theory: VALU-throughput + Ps-write bank conflicts):
//  - Ps chunk-XOR swizzle: chunk c of row r stored at c^(r>>2) -> quads hit
//    disjoint 8-bank ranges -> conflict-free scalar P writes (was 4-way).
//  - row-sum li computed by one extra MFMA against an all-ones B fragment
//    (every output col holds the row sum; layout matches o[tt][r]); removes
//    8 VALU adds/iter and the final shuffle reduction.
//  - exp2 with pre-folded log2(e) (kills the v_mul inside __expf).
//  - s_setprio(1) around MFMA clusters (T5; attn regime, +4-7% per m191).
__global__ __launch_bounds__(256) void attn_kernel(
    const __hip_bfloat16* __restrict__ Q,   // [B,H,S,HD]
    const __hip_bfloat16* __restrict__ K,   // [B,H,S,HD]
    const __hip_bfloat16* __restrict__ Vt,  // [B,H,HD,S]
    const float* __restrict__ mask,         // [B,S] additive fp32
    __hip_bfloat16* __restrict__ ctx) {     // [B,S,D]
    // Ks: 32 keys x 64 hd, packed rows (128 B). LDS slot (row m, chunk p) holds
    // global hd-chunk p^(m&7)  -> reads at chunk q^(m&7): conflict-free phases.
    // Vs: 64 d x 32 keys, packed rows (64 B). slot (d, p) holds key-chunk p^(d&3).
    __shared__ __align__(16) __hip_bfloat16 Ks[2][32 * 64];
    __shared__ __align__(16) __hip_bfloat16 Vs[2][64 * 32];
    __shared__ __align__(16) __hip_bfloat16 Ps[4][16][40];
    const int bh = blockIdx.x;
    const int b = bh >> 4, h = bh & 15;
    const int t = threadIdx.x, wave = t >> 6, lane = t & 63;
    const int quad = lane >> 4, m16 = lane & 15;
    const int qbase = blockIdx.y * 64 + wave * 16;
    const __hip_bfloat16* Qh = Q + (size_t)bh * S_LEN * HD;
    const __hip_bfloat16* Kh = K + (size_t)bh * S_LEN * HD;
    const __hip_bfloat16* Vh = Vt + (size_t)bh * HD * S_LEN;
    const float* mb = mask + (size_t)b * S_LEN;
    const float LOG2E = 1.44269504f;
    const float scale2 = 0.125f * LOG2E;   // softmax scale pre-folded with log2(e)
    const float M_FIX2 = 20.0f * LOG2E;

    // DMA source offsets (swizzled) — wave w stages K rows [w*8,w*8+8), V rows [w*16,w*16+16)
    const int kr = lane >> 3, kc = lane & 7;           // K: row-in-chunk, phys chunk
    const size_t kgoff = (size_t)(wave * 8 + kr) * HD + ((kc ^ (kr & 7)) * 8);
    const int vr = lane >> 2, vc = lane & 3;           // V: row-in-chunk, phys chunk
    const size_t vgoff = (size_t)(wave * 16 + vr) * S_LEN + ((vc ^ (vr & 3)) * 8);
    __hip_bfloat16* kdst0 = &Ks[0][wave * 512]; __hip_bfloat16* kdst1 = &Ks[1][wave * 512];
    __hip_bfloat16* vdst0 = &Vs[0][wave * 512]; __hip_bfloat16* vdst1 = &Vs[1][wave * 512];

    short8 aq0 = *(const short8*)&Qh[(size_t)(qbase + m16) * HD + quad * 8];
    short8 aq1 = *(const short8*)&Qh[(size_t)(qbase + m16) * HD + 32 + quad * 8];

    // all-ones bf16 B-fragment for the row-sum MFMA (1.0 = 0x3F80)
    const short ONEB = (short)0x3F80;
    const short8 ones = {ONEB, ONEB, ONEB, ONEB, ONEB, ONEB, ONEB, ONEB};

    // prologue: DMA tile 0 into buffer 0
    async_ld16(&Kh[kgoff], kdst0);
    async_ld16(&Vh[vgoff], vdst0);
    __syncthreads();

    floatx4 o[4] = {};
    floatx4 lacc = {};

    // swizzled fragment read offsets (elems)
    const int swk = m16 & 7;   // K row swizzle key (rows m16 and 16+m16 share it)
    // Ps chunk-XOR swizzle: logical chunk c of row r lives at phys chunk c^(r>>2).
    // Write side: row = quad*4+r -> key = quad. Loop-invariant per lane:
    const int pc0 = (((m16 >> 3) ^ quad) << 3) | (m16 & 7);          // col m16
    const int pc1 = ((((m16 >> 3) + 2) ^ quad) << 3) | (m16 & 7);    // col 16+m16
    // Read side: row = m16 -> key = (m16>>2)&3, logical chunk = quad:
    const int apoff = (quad ^ ((m16 >> 2) & 3)) * 8;

    for (int it = 0; it < S_LEN / 32; it++) {
        const int k0 = it * 32;
        const int cur = it & 1;
        // issue DMA for next tile into the other buffer (overlaps this iter's compute)
        if (it < S_LEN / 32 - 1) {
            async_ld16(&Kh[(size_t)(k0 + 32) * HD + kgoff], cur ? kdst0 : kdst1);
            async_ld16(&Vh[(size_t)(k0 + 32) + vgoff], cur ? vdst0 : vdst1);
        }

        const __hip_bfloat16* Kc = Ks[cur];
        short8 bk00 = *(const short8*)&Kc[m16 * 64 + ((quad ^ swk) * 8)];
        short8 bk01 = *(const short8*)&Kc[m16 * 64 + (((quad + 4) ^ swk) * 8)];
        short8 bk10 = *(const short8*)&Kc[(16 + m16) * 64 + ((quad ^ swk) * 8)];
        short8 bk11 = *(const short8*)&Kc[(16 + m16) * 64 + (((quad + 4) ^ swk) * 8)];
        floatx4 sc0 = {}, sc1 = {};
        __builtin_amdgcn_s_setprio(1);
        sc0 = __builtin_amdgcn_mfma_f32_16x16x32_bf16(aq0, bk00, sc0, 0, 0, 0);
        sc0 = __builtin_amdgcn_mfma_f32_16x16x32_bf16(aq1, bk01, sc0, 0, 0, 0);
        sc1 = __builtin_amdgcn_mfma_f32_16x16x32_bf16(aq0, bk10, sc1, 0, 0, 0);
        sc1 = __builtin_amdgcn_mfma_f32_16x16x32_bf16(aq1, bk11, sc1, 0, 0, 0);
        __builtin_amdgcn_s_setprio(0);

        float mk0 = mb[k0 + m16] * LOG2E - M_FIX2;
        float mk1 = mb[k0 + 16 + m16] * LOG2E - M_FIX2;
#pragma unroll
        for (int r = 0; r < 4; r++) {
            float p0 = __builtin_amdgcn_exp2f(sc0[r] * scale2 + mk0);
            float p1 = __builtin_amdgcn_exp2f(sc1[r] * scale2 + mk1);
            Ps[wave][quad * 4 + r][pc0] = __float2bfloat16(p0);
            Ps[wave][quad * 4 + r][pc1] = __float2bfloat16(p1);
        }
        short8 ap = *(const short8*)&Ps[wave][m16][apoff];
        const __hip_bfloat16* Vc = Vs[cur];
        __builtin_amdgcn_s_setprio(1);
        lacc = __builtin_amdgcn_mfma_f32_16x16x32_bf16(ap, ones, lacc, 0, 0, 0);
#pragma unroll
        for (int tt = 0; tt < 4; tt++) {
            const int d = tt * 16 + m16;
            short8 bv = *(const short8*)&Vc[d * 32 + ((quad ^ (d & 3)) * 8)];
            o[tt] = __builtin_amdgcn_mfma_f32_16x16x32_bf16(ap, bv, o[tt], 0, 0, 0);
        }
        __builtin_amdgcn_s_setprio(0);
        __syncthreads();  // drains DMA (vmcnt) + barrier: next buffer ready, cur reusable
    }

    // li[r] = row sum of P, delivered by the ones-MFMA in every output column
    float li[4];
#pragma unroll
    for (int r = 0; r < 4; r++) li[r] = 1.0f / lacc[r];
#pragma unroll
    for (int tt = 0; tt < 4; tt++)
#pragma unroll
        for (int r = 0; r < 4; r++) {
            int srow = qbase + quad * 4 + r;
            int d = tt * 16 + m16;
            float v = o[tt][r] * li[r];
            ctx[((size_t)b * S_LEN + srow) * DMODEL + h * HD + d] = __float2bfloat16(v);
        }
}

extern "C" void kernel_launch(void* const* d_in, const int* in_sizes, int n_in,
                              void* d_out, int out_size, void* d_ws, size_t ws_size,
                              hipStream_t stream) {
    (void)in_sizes; (void)n_in; (void)out_size; (void)ws_size;
    const float* hidden = (const float*)d_in[0];  // [2,2048,1024] fp32
    const float* mask   = (const float*)d_in[1];  // [2,1,1,2048] fp32
    const float* Wqkv   = (const float*)d_in[2];  // [1024,3072] fp32 [in,out]
    const float* bqkv   = (const float*)d_in[3];  // [3072] fp32
    const float* Wproj  = (const float*)d_in[4];  // [1024,1024] fp32 [in,out]
    const float* bproj  = (const float*)d_in[5];  // [1024] fp32
    float* out = (float*)d_out;                   // fp32 output

    // ---- workspace layout (peak 19M bf16 elems = 38 MB) ----
    __hip_bfloat16* ws = (__hip_bfloat16*)d_ws;
    const size_t Q4 = 4u * 1024 * 1024;
    __hip_bfloat16* Qp      = ws;
    __hip_bfloat16* Kp      = ws + 1 * Q4;
    __hip_bfloat16* Vt      = ws + 2 * Q4;
    __hip_bfloat16* hid_bf  = ws + 3 * Q4;
    __hip_bfloat16* ctx     = ws + 3 * Q4;   // overlaps hid_bf (disjoint lifetime)
    __hip_bfloat16* Wqkv_t  = ws + 4 * Q4;
    __hip_bfloat16* Wproj_t = ws + 4 * Q4;   // overlaps Wqkv_t (disjoint lifetime)

    cvt_kernel<<<dim3(4 * 1024 * 1024 / 2048), 256, 0, stream>>>(hidden, hid_bf);
    transpose_kernel<<<dim3(3072 / 32, 1024 / 32), dim3(32, 8), 0, stream>>>(Wqkv, Wqkv_t, 1024, 3072);

    // QKV projection + scatter: M=4096, N=3072, K=1024
    gemm128<<<dim3(3072 / 128, 4096 / 128), 256, 0, stream>>>(
        hid_bf, Wqkv_t, bqkv, nullptr, Qp, Kp, Vt, BATCH * S_LEN, 3 * DMODEL, DMODEL, 1);

    transpose_kernel<<<dim3(1024 / 32, 1024 / 32), dim3(32, 8), 0, stream>>>(Wproj, Wproj_t, 1024, 1024);

    attn_kernel<<<dim3(BATCH * NH, S_LEN / 64), 256, 0, stream>>>(Qp, Kp, Vt, mask, ctx);

    // output projection: M=4096, N=1024, K=1024 -> fp32 out
    gemm128<<<dim3(1024 / 128, 4096 / 128), 256, 0, stream>>>(
        ctx, Wproj_t, bproj, out, nullptr, nullptr, nullptr, BATCH * S_LEN, DMODEL, DMODEL, 0);
}

// Round 3
// 219.384 us; speedup vs baseline: 1.0415x; 1.0415x over previous
//
#include <hip/hip_runtime.h>
#include <hip/hip_bf16.h>

typedef short short8 __attribute__((ext_vector_type(8)));
typedef float floatx4 __attribute__((ext_vector_type(4)));
typedef int intx4 __attribute__((ext_vector_type(4)));

#define S_LEN 2048
#define DMODEL 1024
#define NH 16
#define HD 64
#define BATCH 2

static __device__ __forceinline__ short f2bf(float x) {
    __hip_bfloat16 h = __float2bfloat16(x);
    return *(short*)&h;
}

static __device__ __forceinline__ unsigned pk2(float lo, float hi) {
    // packed bf16 pair; compiler fuses to v_cvt_pk_bf16_f32 (m240: don't hand-asm)
    unsigned a = (unsigned)(unsigned short)f2bf(lo);
    unsigned b = (unsigned)(unsigned short)f2bf(hi);
    return a | (b << 16);
}

// async 16B global->LDS (wave-uniform LDS base + lane*16 contract)
static __device__ __forceinline__ void async_ld16(const __hip_bfloat16* g, __hip_bfloat16* l) {
    __builtin_amdgcn_global_load_lds(
        (const __attribute__((address_space(1))) unsigned int*)g,
        (__attribute__((address_space(3))) unsigned int*)l, 16, 0, 0);
}

// ---------------- fp32 -> bf16 bulk convert ----------------
__global__ __launch_bounds__(256) void cvt_kernel(const float* __restrict__ X,
                                                  __hip_bfloat16* __restrict__ Y) {
    int i = (blockIdx.x * 256 + threadIdx.x) * 8;
    floatx4 f0 = *(const floatx4*)&X[i];
    floatx4 f1 = *(const floatx4*)&X[i + 4];
    short8 s;
    s[0] = f2bf(f0[0]); s[1] = f2bf(f0[1]); s[2] = f2bf(f0[2]); s[3] = f2bf(f0[3]);
    s[4] = f2bf(f1[0]); s[5] = f2bf(f1[1]); s[6] = f2bf(f1[2]); s[7] = f2bf(f1[3]);
    *(short8*)&Y[i] = s;
}

// ---------------- weight transpose + downcast: Wt[N][K] = bf16(W[K][N]) ----------------
__global__ void transpose_kernel(const float* __restrict__ W,
                                 __hip_bfloat16* __restrict__ Wt, int K, int N) {
    __shared__ float tile[32][33];
    int n0 = blockIdx.x * 32, k0 = blockIdx.y * 32;
    int tx = threadIdx.x, ty = threadIdx.y;  // blockDim = (32,8)
#pragma unroll
    for (int i = 0; i < 32; i += 8)
        tile[ty + i][tx] = W[(size_t)(k0 + ty + i) * N + n0 + tx];
    __syncthreads();
#pragma unroll
    for (int i = 0; i < 32; i += 8)
        Wt[(size_t)(n0 + ty + i) * K + k0 + tx] = __float2bfloat16(tile[tx][ty + i]);
}

// ---------------- MFMA GEMM v2: 128x128 tile, BK=32, global_load_lds (unchanged) ----------------
__global__ __launch_bounds__(256) void gemm128(
    const __hip_bfloat16* __restrict__ A, const __hip_bfloat16* __restrict__ Bt,
    const float* __restrict__ bias, float* __restrict__ Cf,
    __hip_bfloat16* __restrict__ Qp, __hip_bfloat16* __restrict__ Kp,
    __hip_bfloat16* __restrict__ Vt, int M, int N, int K, int mode) {
    __shared__ __align__(16) __hip_bfloat16 As[128 * 32];
    __shared__ __align__(16) __hip_bfloat16 Bs[128 * 32];
    const int m0 = blockIdx.y * 128, n0 = blockIdx.x * 128;
    const int t = threadIdx.x;
    const int wave = t >> 6, lane = t & 63;
    const int quad = lane >> 4, m16 = lane & 15;
    const int wm = (wave >> 1) * 64, wn = (wave & 1) * 64;
    const int srow = lane >> 2, scol = (lane & 3) * 8;

    floatx4 acc[4][4] = {};
    for (int k0 = 0; k0 < K; k0 += 32) {
#pragma unroll
        for (int i = 0; i < 2; i++) {
            const int rbase = wave * 32 + i * 16;
            async_ld16(&A[(size_t)(m0 + rbase + srow) * K + k0 + scol], &As[rbase * 32]);
            async_ld16(&Bt[(size_t)(n0 + rbase + srow) * K + k0 + scol], &Bs[rbase * 32]);
        }
        __syncthreads();
        short8 af[4], bfr[4];
#pragma unroll
        for (int i = 0; i < 4; i++)
            af[i] = *(const short8*)&As[(wm + i * 16 + m16) * 32 + quad * 8];
#pragma unroll
        for (int j = 0; j < 4; j++)
            bfr[j] = *(const short8*)&Bs[(wn + j * 16 + m16) * 32 + quad * 8];
#pragma unroll
        for (int i = 0; i < 4; i++)
#pragma unroll
            for (int j = 0; j < 4; j++)
                acc[i][j] = __builtin_amdgcn_mfma_f32_16x16x32_bf16(af[i], bfr[j], acc[i][j], 0, 0, 0);
        __syncthreads();
    }
#pragma unroll
    for (int i = 0; i < 4; i++)
#pragma unroll
        for (int j = 0; j < 4; j++) {
            int col = n0 + wn + j * 16 + m16;
            float bv = bias[col];
#pragma unroll
            for (int r = 0; r < 4; r++) {
                int row = m0 + wm + i * 16 + quad * 4 + r;
                float v = acc[i][j][r] + bv;
                if (mode == 0) {
                    Cf[(size_t)row * N + col] = v;
                } else {
                    __hip_bfloat16 hv = __float2bfloat16(v);
                    int tt = col >> 10, rem = col & 1023;
                    int h = rem >> 6, d = rem & 63;
                    int b = row >> 11, s = row & 2047;
                    if (tt == 0)      Qp[((size_t)(b * NH + h) * S_LEN + s) * HD + d] = hv;
                    else if (tt == 1) Kp[((size_t)(b * NH + h) * S_LEN + s) * HD + d] = hv;
                    else              Vt[((size_t)(b * NH + h) * HD + d) * S_LEN + s] = hv;
                }
            }
        }
}

// ---------------- MFMA flash attention v7: swapped QK^T, chunk-exchange softmax ----------------
// grid (B*H, S/64), block 256 (4 waves); each wave owns 16 queries, 64 keys/step.
// v7 fixes v6's broken redistribution. Instead of moving P into the canonical
// A-fragment layout, we exploit the PV MFMA's kk-permutation freedom: within one
// 16x16x32 MFMA the 32 contraction slots may map to ANY 32 keys as long as the
// V-side B-fragment reads the same keys. After swapped QK^T, lane quad holds keys
// 16kt + 4quad + {0..3}; the other half of each aligned 8-key chunk lives in lane
// quad^1 (= lane^16, ds_swizzle 0x401F, semantics per ISA appendix). One 4-dword
// exchange + cndmask assembly gives lane quad full chunks cA=((quad&1)<<2)|(quad>>1)
// and cB=cA|2 (chunks {0,1,4,5} -> MFMA-A, {2,3,6,7} -> MFMA-B, disjoint+complete);
// V fragments read slot c^(d&7) for exactly those chunks. No Ps LDS, no permlane.
__global__ __launch_bounds__(256, 4) void attn_kernel(
    const __hip_bfloat16* __restrict__ Q,   // [B,H,S,HD]
    const __hip_bfloat16* __restrict__ K,   // [B,H,S,HD]
    const __hip_bfloat16* __restrict__ Vt,  // [B,H,HD,S]
    const float* __restrict__ mask,         // [B,S] additive fp32
    __hip_bfloat16* __restrict__ ctx) {     // [B,S,D]
    // Ks: 64 keys x 64 hd, packed rows (128 B). slot (row, p) holds global hd-chunk
    // p^(row&7) -> fragment reads at chunk q^(row&7) are conflict-free.
    // Vs: 64 d x 64 keys, packed rows. slot (d, p) holds global key-chunk p^(d&7).
    __shared__ __align__(16) __hip_bfloat16 Ks[2][64 * 64];
    __shared__ __align__(16) __hip_bfloat16 Vs[2][64 * 64];
    const int bh = blockIdx.x;
    const int b = bh >> 4, h = bh & 15;
    const int t = threadIdx.x, wave = t >> 6, lane = t & 63;
    const int quad = lane >> 4, m16 = lane & 15;
    const int qbase = blockIdx.y * 64 + wave * 16;
    const __hip_bfloat16* Qh = Q + (size_t)bh * S_LEN * HD;
    const __hip_bfloat16* Kh = K + (size_t)bh * S_LEN * HD;
    const __hip_bfloat16* Vh = Vt + (size_t)bh * HD * S_LEN;
    const float* mb = mask + (size_t)b * S_LEN;
    const float LOG2E = 1.44269504f;
    const float scale2 = 0.125f * LOG2E;   // softmax scale pre-folded with log2(e)
    const float M_FIX2 = 20.0f * LOG2E;    // fixed-max bias (cancels in o/li)

    // DMA source offsets (int, swizzled). Wave w stages rows [w*16, w*16+16) of both
    // K (keys x hd) and V^T (d x keys), as 2 issues of 8 rows (1 KB) each.
    const int r8 = lane >> 3, c8 = lane & 7;
    const int kg0 = (wave * 16 + r8) * HD + ((c8 ^ r8) * 8);
    const int kg1 = (wave * 16 + 8 + r8) * HD + ((c8 ^ r8) * 8);
    const int vg0 = (wave * 16 + r8) * S_LEN + ((c8 ^ r8) * 8);
    const int vg1 = (wave * 16 + 8 + r8) * S_LEN + ((c8 ^ r8) * 8);

    // Q fragments (B-operand: lane m16 <-> query m16, chunk quad <-> hd)
    short8 aq0 = *(const short8*)&Qh[(size_t)(qbase + m16) * HD + quad * 8];
    short8 aq1 = *(const short8*)&Qh[(size_t)(qbase + m16) * HD + 32 + quad * 8];

    const short ONEB = (short)0x3F80;  // bf16 1.0
    const short8 ones = {ONEB, ONEB, ONEB, ONEB, ONEB, ONEB, ONEB, ONEB};

    // prologue: DMA tile 0 into buffer 0
    {
        __hip_bfloat16* kd = &Ks[0][wave * 16 * 64];
        async_ld16(&Kh[kg0], kd);
        async_ld16(&Kh[kg1], kd + 512);
        __hip_bfloat16* vd = &Vs[0][wave * 16 * 64];
        async_ld16(&Vh[vg0], vd);
        async_ld16(&Vh[vg1], vd + 512);
    }
    __syncthreads();

    floatx4 o[4] = {};
    floatx4 lacc = {};
    const int swk = m16 & 7;                     // K fragment-read swizzle key (row&7)
    const int e = quad & 1;                      // chunk-exchange parity (lane bit4)
    const int cA = ((quad & 1) << 2) | (quad >> 1);  // chunk ids owned after exchange
    const int cB = cA | 2;
    const int vsA = (cA ^ swk) * 8;              // V-slot offsets ((d&7) == (m16&7))
    const int vsB = (cB ^ swk) * 8;

    for (int it = 0; it < S_LEN / 64; it++) {
        const int k0 = it * 64;
        const int cur = it & 1;
        // issue DMA for next tile into the other buffer (overlaps this iter's compute)
        if (it < S_LEN / 64 - 1) {
            __hip_bfloat16* kd = &Ks[cur ^ 1][wave * 16 * 64];
            async_ld16(&Kh[(k0 + 64) * HD + kg0], kd);
            async_ld16(&Kh[(k0 + 64) * HD + kg1], kd + 512);
            __hip_bfloat16* vd = &Vs[cur ^ 1][wave * 16 * 64];
            async_ld16(&Vh[(k0 + 64) + vg0], vd);
            async_ld16(&Vh[(k0 + 64) + vg1], vd + 512);
        }

        // ---- QK^T (swapped): sc[kt][r] = S[key = kt*16+quad*4+r][q = m16] ----
        const __hip_bfloat16* Kc = Ks[cur];
        floatx4 sc[4] = {};
        __builtin_amdgcn_s_setprio(1);
#pragma unroll
        for (int kt = 0; kt < 4; kt++) {
            const int row = kt * 16 + m16;
            short8 ak0 = *(const short8*)&Kc[row * 64 + ((quad ^ swk) * 8)];
            short8 ak1 = *(const short8*)&Kc[row * 64 + (((quad + 4) ^ swk) * 8)];
            sc[kt] = __builtin_amdgcn_mfma_f32_16x16x32_bf16(ak0, aq0, sc[kt], 0, 0, 0);
            sc[kt] = __builtin_amdgcn_mfma_f32_16x16x32_bf16(ak1, aq1, sc[kt], 0, 0, 0);
        }
        __builtin_amdgcn_s_setprio(0);

        // ---- softmax numerator (in-register) + pack to bf16 dword pairs ----
        // dk[kt][w] = keys {16kt + 4quad + 2w, +2w+1} for query m16 (lo,hi order)
        unsigned dk[4][2];
#pragma unroll
        for (int kt = 0; kt < 4; kt++) {
            floatx4 mv = *(const floatx4*)&mb[k0 + kt * 16 + quad * 4];
            float p0 = __builtin_amdgcn_exp2f(
                __builtin_fmaf(sc[kt][0], scale2, __builtin_fmaf(mv[0], LOG2E, -M_FIX2)));
            float p1 = __builtin_amdgcn_exp2f(
                __builtin_fmaf(sc[kt][1], scale2, __builtin_fmaf(mv[1], LOG2E, -M_FIX2)));
            float p2 = __builtin_amdgcn_exp2f(
                __builtin_fmaf(sc[kt][2], scale2, __builtin_fmaf(mv[2], LOG2E, -M_FIX2)));
            float p3 = __builtin_amdgcn_exp2f(
                __builtin_fmaf(sc[kt][3], scale2, __builtin_fmaf(mv[3], LOG2E, -M_FIX2)));
            dk[kt][0] = pk2(p0, p1);
            dk[kt][1] = pk2(p2, p3);
        }

        // ---- chunk exchange with lane^16 (quad^1): assemble full 8-key chunks ----
        // even lane keeps kt∈{0,1} chunks, odd keeps kt∈{2,3}; partner supplies the
        // other 4-key half of each chunk. ds_swizzle 0x401F = xor-16 (ISA appendix).
        unsigned t0 = e ? dk[0][0] : dk[2][0];
        unsigned t1 = e ? dk[0][1] : dk[2][1];
        unsigned t2 = e ? dk[1][0] : dk[3][0];
        unsigned t3 = e ? dk[1][1] : dk[3][1];
        unsigned r0 = (unsigned)__builtin_amdgcn_ds_swizzle((int)t0, 0x401F);
        unsigned r1 = (unsigned)__builtin_amdgcn_ds_swizzle((int)t1, 0x401F);
        unsigned r2 = (unsigned)__builtin_amdgcn_ds_swizzle((int)t2, 0x401F);
        unsigned r3 = (unsigned)__builtin_amdgcn_ds_swizzle((int)t3, 0x401F);
        intx4 wa, wb;
        wa[0] = (int)(e ? r0 : dk[0][0]);   // chunk cA keys {8cA+0,1}
        wa[1] = (int)(e ? r1 : dk[0][1]);   // {8cA+2,3}
        wa[2] = (int)(e ? dk[2][0] : r0);   // {8cA+4,5}
        wa[3] = (int)(e ? dk[2][1] : r1);   // {8cA+6,7}
        wb[0] = (int)(e ? r2 : dk[1][0]);   // chunk cB keys {8cB+0,1}
        wb[1] = (int)(e ? r3 : dk[1][1]);
        wb[2] = (int)(e ? dk[3][0] : r2);
        wb[3] = (int)(e ? dk[3][1] : r3);
        short8 apA = *(short8*)&wa;
        short8 apB = *(short8*)&wb;

        // ---- PV + row-sum (ones); V-side reads the SAME chunks cA/cB ----
        const __hip_bfloat16* Vc = Vs[cur];
        __builtin_amdgcn_s_setprio(1);
        lacc = __builtin_amdgcn_mfma_f32_16x16x32_bf16(apA, ones, lacc, 0, 0, 0);
        lacc = __builtin_amdgcn_mfma_f32_16x16x32_bf16(apB, ones, lacc, 0, 0, 0);
#pragma unroll
        for (int tt = 0; tt < 4; tt++) {
            const int d = tt * 16 + m16;
            short8 bvA = *(const short8*)&Vc[d * 64 + vsA];
            short8 bvB = *(const short8*)&Vc[d * 64 + vsB];
            o[tt] = __builtin_amdgcn_mfma_f32_16x16x32_bf16(apA, bvA, o[tt], 0, 0, 0);
            o[tt] = __builtin_amdgcn_mfma_f32_16x16x32_bf16(apB, bvB, o[tt], 0, 0, 0);
        }
        __builtin_amdgcn_s_setprio(0);
        __syncthreads();  // drains DMA (vmcnt) + barrier: next buffer ready, cur reusable
    }

    // li[r] = row sum of P (q = quad*4+r), delivered by the ones-MFMAs
    float li[4];
#pragma unroll
    for (int r = 0; r < 4; r++) li[r] = 1.0f / lacc[r];
#pragma unroll
    for (int tt = 0; tt < 4; tt++)
#pragma unroll
        for (int r = 0; r < 4; r++) {
            int srow = qbase + quad * 4 + r;
            int d = tt * 16 + m16;
            float v = o[tt][r] * li[r];
            ctx[((size_t)b * S_LEN + srow) * DMODEL + h * HD + d] = __float2bfloat16(v);
        }
}

extern "C" void kernel_launch(void* const* d_in, const int* in_sizes, int n_in,
                              void* d_out, int out_size, void* d_ws, size_t ws_size,
                              hipStream_t stream) {
    (void)in_sizes; (void)n_in; (void)out_size; (void)ws_size;
    const float* hidden = (const float*)d_in[0];  // [2,2048,1024] fp32
    const float* mask   = (const float*)d_in[1];  // [2,1,1,2048] fp32
    const float* Wqkv   = (const float*)d_in[2];  // [1024,3072] fp32 [in,out]
    const float* bqkv   = (const float*)d_in[3];  // [3072] fp32
    const float* Wproj  = (const float*)d_in[4];  // [1024,1024] fp32 [in,out]
    const float* bproj  = (const float*)d_in[5];  // [1024] fp32
    float* out = (float*)d_out;                   // fp32 output

    // ---- workspace layout (peak 19M bf16 elems = 38 MB) ----
    __hip_bfloat16* ws = (__hip_bfloat16*)d_ws;
    const size_t Q4 = 4u * 1024 * 1024;
    __hip_bfloat16* Qp      = ws;
    __hip_bfloat16* Kp      = ws + 1 * Q4;
    __hip_bfloat16* Vt      = ws + 2 * Q4;
    __hip_bfloat16* hid_bf  = ws + 3 * Q4;
    __hip_bfloat16* ctx     = ws + 3 * Q4;   // overlaps hid_bf (disjoint lifetime)
    __hip_bfloat16* Wqkv_t  = ws + 4 * Q4;
    __hip_bfloat16* Wproj_t = ws + 4 * Q4;   // overlaps Wqkv_t (disjoint lifetime)

    cvt_kernel<<<dim3(4 * 1024 * 1024 / 2048), 256, 0, stream>>>(hidden, hid_bf);
    transpose_kernel<<<dim3(3072 / 32, 1024 / 32), dim3(32, 8), 0, stream>>>(Wqkv, Wqkv_t, 1024, 3072);

    // QKV projection + scatter: M=4096, N=3072, K=1024
    gemm128<<<dim3(3072 / 128, 4096 / 128), 256, 0, stream>>>(
        hid_bf, Wqkv_t, bqkv, nullptr, Qp, Kp, Vt, BATCH * S_LEN, 3 * DMODEL, DMODEL, 1);

    transpose_kernel<<<dim3(1024 / 32, 1024 / 32), dim3(32, 8), 0, stream>>>(Wproj, Wproj_t, 1024, 1024);

    attn_kernel<<<dim3(BATCH * NH, S_LEN / 64), 256, 0, stream>>>(Qp, Kp, Vt, mask, ctx);

    // output projection: M=4096, N=1024, K=1024 -> fp32 out
    gemm128<<<dim3(1024 / 128, 4096 / 128), 256, 0, stream>>>(
        ctx, Wproj_t, bproj, out, nullptr, nullptr, nullptr, BATCH * S_LEN, DMODEL, DMODEL, 0);
}

// Round 4
// 218.686 us; speedup vs baseline: 1.0448x; 1.0032x over previous
//
#include <hip/hip_runtime.h>
#include <hip/hip_bf16.h>

typedef short short8 __attribute__((ext_vector_type(8)));
typedef float floatx4 __attribute__((ext_vector_type(4)));
typedef int intx4 __attribute__((ext_vector_type(4)));

#define S_LEN 2048
#define DMODEL 1024
#define NH 16
#define HD 64
#define BATCH 2

static __device__ __forceinline__ short f2bf(float x) {
    __hip_bfloat16 h = __float2bfloat16(x);
    return *(short*)&h;
}

static __device__ __forceinline__ unsigned pk2(float lo, float hi) {
    // packed bf16 pair; compiler fuses to v_cvt_pk_bf16_f32 (m240: don't hand-asm)
    unsigned a = (unsigned)(unsigned short)f2bf(lo);
    unsigned b = (unsigned)(unsigned short)f2bf(hi);
    return a | (b << 16);
}

// async 16B global->LDS (wave-uniform LDS base + lane*16 contract)
static __device__ __forceinline__ void async_ld16(const __hip_bfloat16* g, __hip_bfloat16* l) {
    __builtin_amdgcn_global_load_lds(
        (const __attribute__((address_space(1))) unsigned int*)g,
        (__attribute__((address_space(3))) unsigned int*)l, 16, 0, 0);
}

// ---------------- fp32 -> bf16 bulk convert ----------------
__global__ __launch_bounds__(256) void cvt_kernel(const float* __restrict__ X,
                                                  __hip_bfloat16* __restrict__ Y) {
    int i = (blockIdx.x * 256 + threadIdx.x) * 8;
    floatx4 f0 = *(const floatx4*)&X[i];
    floatx4 f1 = *(const floatx4*)&X[i + 4];
    short8 s;
    s[0] = f2bf(f0[0]); s[1] = f2bf(f0[1]); s[2] = f2bf(f0[2]); s[3] = f2bf(f0[3]);
    s[4] = f2bf(f1[0]); s[5] = f2bf(f1[1]); s[6] = f2bf(f1[2]); s[7] = f2bf(f1[3]);
    *(short8*)&Y[i] = s;
}

// ---------------- weight transpose + downcast: Wt[N][K] = bf16(W[K][N]) ----------------
__global__ void transpose_kernel(const float* __restrict__ W,
                                 __hip_bfloat16* __restrict__ Wt, int K, int N) {
    __shared__ float tile[32][33];
    int n0 = blockIdx.x * 32, k0 = blockIdx.y * 32;
    int tx = threadIdx.x, ty = threadIdx.y;  // blockDim = (32,8)
#pragma unroll
    for (int i = 0; i < 32; i += 8)
        tile[ty + i][tx] = W[(size_t)(k0 + ty + i) * N + n0 + tx];
    __syncthreads();
#pragma unroll
    for (int i = 0; i < 32; i += 8)
        Wt[(size_t)(n0 + ty + i) * K + k0 + tx] = __float2bfloat16(tile[tx][ty + i]);
}

// ---------------- MFMA GEMM v2: 128x128 tile, BK=32, global_load_lds (unchanged) ----------------
__global__ __launch_bounds__(256) void gemm128(
    const __hip_bfloat16* __restrict__ A, const __hip_bfloat16* __restrict__ Bt,
    const float* __restrict__ bias, float* __restrict__ Cf,
    __hip_bfloat16* __restrict__ Qp, __hip_bfloat16* __restrict__ Kp,
    __hip_bfloat16* __restrict__ Vt, int M, int N, int K, int mode) {
    __shared__ __align__(16) __hip_bfloat16 As[128 * 32];
    __shared__ __align__(16) __hip_bfloat16 Bs[128 * 32];
    const int m0 = blockIdx.y * 128, n0 = blockIdx.x * 128;
    const int t = threadIdx.x;
    const int wave = t >> 6, lane = t & 63;
    const int quad = lane >> 4, m16 = lane & 15;
    const int wm = (wave >> 1) * 64, wn = (wave & 1) * 64;
    const int srow = lane >> 2, scol = (lane & 3) * 8;

    floatx4 acc[4][4] = {};
    for (int k0 = 0; k0 < K; k0 += 32) {
#pragma unroll
        for (int i = 0; i < 2; i++) {
            const int rbase = wave * 32 + i * 16;
            async_ld16(&A[(size_t)(m0 + rbase + srow) * K + k0 + scol], &As[rbase * 32]);
            async_ld16(&Bt[(size_t)(n0 + rbase + srow) * K + k0 + scol], &Bs[rbase * 32]);
        }
        __syncthreads();
        short8 af[4], bfr[4];
#pragma unroll
        for (int i = 0; i < 4; i++)
            af[i] = *(const short8*)&As[(wm + i * 16 + m16) * 32 + quad * 8];
#pragma unroll
        for (int j = 0; j < 4; j++)
            bfr[j] = *(const short8*)&Bs[(wn + j * 16 + m16) * 32 + quad * 8];
#pragma unroll
        for (int i = 0; i < 4; i++)
#pragma unroll
            for (int j = 0; j < 4; j++)
                acc[i][j] = __builtin_amdgcn_mfma_f32_16x16x32_bf16(af[i], bfr[j], acc[i][j], 0, 0, 0);
        __syncthreads();
    }
#pragma unroll
    for (int i = 0; i < 4; i++)
#pragma unroll
        for (int j = 0; j < 4; j++) {
            int col = n0 + wn + j * 16 + m16;
            float bv = bias[col];
#pragma unroll
            for (int r = 0; r < 4; r++) {
                int row = m0 + wm + i * 16 + quad * 4 + r;
                float v = acc[i][j][r] + bv;
                if (mode == 0) {
                    Cf[(size_t)row * N + col] = v;
                } else {
                    __hip_bfloat16 hv = __float2bfloat16(v);
                    int tt = col >> 10, rem = col & 1023;
                    int h = rem >> 6, d = rem & 63;
                    int b = row >> 11, s = row & 2047;
                    if (tt == 0)      Qp[((size_t)(b * NH + h) * S_LEN + s) * HD + d] = hv;
                    else if (tt == 1) Kp[((size_t)(b * NH + h) * S_LEN + s) * HD + d] = hv;
                    else              Vt[((size_t)(b * NH + h) * HD + d) * S_LEN + s] = hv;
                }
            }
        }
}

// ---------------- MFMA flash attention v8: in-block split-K, 8 waves ----------------
// grid (B*H, S/64), block 512 (8 waves = 2 teams x 4 waves).
// Team 0 (waves 0-3): keys [0,1024); team 1 (waves 4-7): keys [1024,2048).
// Wave tw in each team owns queries qb*64 + tw*16. KVBLK=32 per team iter.
// Rationale (counters r3): latency-bound at 4 waves/SIMD (54% stall per slot,
// LDS pipe at 25%, VALU 50%, Mfma 22%). Total waves are pinned by the query
// decomposition; split-K doubles concurrency to 8 waves/SIMD. Fixed-max
// softmax makes partials additive: merge is o=oA+oB, l=lA+lB in LDS (reused).
// Chunk-exchange rederived for KVBLK=32: lane quad assembles 8-key chunk
// C(quad)=((quad&1)<<1)|(quad>>1) via one ds_swizzle(xor16) round; V tile
// [64d][32k] stored with chunk swizzle g(d)=(d>>1)&3 so PV B-reads spread banks.
__global__ __launch_bounds__(512, 8) void attn_kernel(
    const __hip_bfloat16* __restrict__ Q,   // [B,H,S,HD]
    const __hip_bfloat16* __restrict__ K,   // [B,H,S,HD]
    const __hip_bfloat16* __restrict__ Vt,  // [B,H,HD,S]
    const float* __restrict__ mask,         // [B,S] additive fp32
    __hip_bfloat16* __restrict__ ctx) {     // [B,S,D]
    // smem (32 KB): per team 16 KB = Ks dbuf 2x[32*64] + Vs dbuf 2x[64*32].
    // After the loop the whole array is reused as the fp32 merge buffer.
    __shared__ __align__(16) __hip_bfloat16 smem[16384];
    const int bh = blockIdx.x;
    const int b = bh >> 4, h = bh & 15;
    const int t = threadIdx.x, wave = t >> 6, lane = t & 63;
    const int team = wave >> 2, tw = wave & 3;
    const int quad = lane >> 4, m16 = lane & 15;
    const int qbase = blockIdx.y * 64 + tw * 16;
    const int ko = team * (S_LEN / 2);      // this team's key offset
    const __hip_bfloat16* Qh = Q + (size_t)bh * S_LEN * HD;
    const __hip_bfloat16* Kh = K + (size_t)bh * S_LEN * HD;
    const __hip_bfloat16* Vh = Vt + (size_t)bh * HD * S_LEN;
    const float* mb = mask + (size_t)b * S_LEN;
    const float LOG2E = 1.44269504f;
    const float scale2 = 0.125f * LOG2E;    // softmax scale pre-folded with log2(e)
    const float M_FIX2 = 20.0f * LOG2E;     // fixed-max bias (cancels in o/li)

    __hip_bfloat16* Ksb = smem + team * 8192;          // 2 bufs x 2048 elems
    __hip_bfloat16* Vsb = smem + team * 8192 + 4096;   // 2 bufs x 2048 elems

    // DMA source offsets (per-lane, swizzled) and LDS dsts.
    // K tile [32 keys][64 hd], 128B rows; wave tw stages rows [tw*8, tw*8+8)
    // (1 issue). LDS slot (row,p) holds global hd-chunk p^(row&7); row&7 == kr.
    const int kr = lane >> 3, kc = lane & 7;
    const int kgoff = (tw * 8 + kr) * HD + ((kc ^ kr) * 8);
    // V tile [64 d][32 keys], 64B rows; wave tw stages rows [tw*16, tw*16+16)
    // (1 issue). LDS slot (d,p) holds global key-chunk p^g(d), g(d)=(d>>1)&3.
    const int vr = lane >> 2, vc = lane & 3;
    const int vd = tw * 16 + vr;
    const int vgoff = vd * S_LEN + (((vc ^ ((vd >> 1) & 3))) * 8);
    __hip_bfloat16* kdst0 = Ksb + tw * 512;
    __hip_bfloat16* kdst1 = Ksb + 2048 + tw * 512;
    __hip_bfloat16* vdst0 = Vsb + tw * 512;
    __hip_bfloat16* vdst1 = Vsb + 2048 + tw * 512;

    // Q fragments (B-operand: lane m16 <-> query m16, chunk quad <-> hd)
    short8 aq0 = *(const short8*)&Qh[(size_t)(qbase + m16) * HD + quad * 8];
    short8 aq1 = *(const short8*)&Qh[(size_t)(qbase + m16) * HD + 32 + quad * 8];

    const short ONEB = (short)0x3F80;  // bf16 1.0
    const short8 ones = {ONEB, ONEB, ONEB, ONEB, ONEB, ONEB, ONEB, ONEB};

    // prologue: DMA tile 0 into buffer 0
    async_ld16(&Kh[(size_t)ko * HD + kgoff], kdst0);
    async_ld16(&Vh[(size_t)ko + vgoff], vdst0);
    __syncthreads();

    floatx4 o[4] = {};
    floatx4 lacc = {};
    const int swk = m16 & 7;                          // K fragment-read swizzle key
    const int e = quad & 1;                           // exchange parity
    const int C = ((quad & 1) << 1) | (quad >> 1);    // owned 8-key chunk (0,2,1,3)
    const int vsl = (C ^ ((m16 >> 1) & 3)) * 8;       // V-slot offset (g(d)=(m16>>1)&3)

    const int NIT = (S_LEN / 2) / 32;  // 32 iterations of 32 keys per team
    for (int it = 0; it < NIT; it++) {
        const int k0 = it * 32;
        const int cur = it & 1;
        // issue DMA for next tile into the other buffer (overlaps this iter's compute)
        if (it < NIT - 1) {
            async_ld16(&Kh[(size_t)(ko + k0 + 32) * HD + kgoff], cur ? kdst0 : kdst1);
            async_ld16(&Vh[(size_t)(ko + k0 + 32) + vgoff], cur ? vdst0 : vdst1);
        }

        // ---- QK^T (swapped): sc[kt][r] = S[key = 16kt+4quad+r][q = m16] ----
        const __hip_bfloat16* Kc = Ksb + cur * 2048;
        floatx4 sc[2] = {};
        __builtin_amdgcn_s_setprio(1);
#pragma unroll
        for (int kt = 0; kt < 2; kt++) {
            const int row = kt * 16 + m16;
            short8 ak0 = *(const short8*)&Kc[row * 64 + ((quad ^ swk) * 8)];
            short8 ak1 = *(const short8*)&Kc[row * 64 + (((quad + 4) ^ swk) * 8)];
            sc[kt] = __builtin_amdgcn_mfma_f32_16x16x32_bf16(ak0, aq0, sc[kt], 0, 0, 0);
            sc[kt] = __builtin_amdgcn_mfma_f32_16x16x32_bf16(ak1, aq1, sc[kt], 0, 0, 0);
        }
        __builtin_amdgcn_s_setprio(0);

        // ---- softmax numerator (in-register) + pack to bf16 dword pairs ----
        // dk[kt][w] = keys {16kt+4quad+2w, +2w+1} for query m16
        unsigned dk[2][2];
#pragma unroll
        for (int kt = 0; kt < 2; kt++) {
            floatx4 mv = *(const floatx4*)&mb[ko + k0 + kt * 16 + quad * 4];
            float p0 = __builtin_amdgcn_exp2f(
                __builtin_fmaf(sc[kt][0], scale2, __builtin_fmaf(mv[0], LOG2E, -M_FIX2)));
            float p1 = __builtin_amdgcn_exp2f(
                __builtin_fmaf(sc[kt][1], scale2, __builtin_fmaf(mv[1], LOG2E, -M_FIX2)));
            float p2 = __builtin_amdgcn_exp2f(
                __builtin_fmaf(sc[kt][2], scale2, __builtin_fmaf(mv[2], LOG2E, -M_FIX2)));
            float p3 = __builtin_amdgcn_exp2f(
                __builtin_fmaf(sc[kt][3], scale2, __builtin_fmaf(mv[3], LOG2E, -M_FIX2)));
            dk[kt][0] = pk2(p0, p1);
            dk[kt][1] = pk2(p2, p3);
        }

        // ---- chunk exchange with lane^16 (quad^1): assemble chunk C(quad) ----
        // Even quad: low half mine (dk[0]), high half from partner (their dk[0]).
        // Odd quad: low half from partner (their dk[1]), high half mine (dk[1]).
        // Send dk[1-e][w]; receive partner's dk[e][w] via ds_swizzle xor-16.
        unsigned s0 = e ? dk[0][0] : dk[1][0];
        unsigned s1 = e ? dk[0][1] : dk[1][1];
        unsigned r0 = (unsigned)__builtin_amdgcn_ds_swizzle((int)s0, 0x401F);
        unsigned r1 = (unsigned)__builtin_amdgcn_ds_swizzle((int)s1, 0x401F);
        intx4 wa;
        wa[0] = (int)(e ? r0 : dk[0][0]);   // keys 8C+0,1
        wa[1] = (int)(e ? r1 : dk[0][1]);   // keys 8C+2,3
        wa[2] = (int)(e ? dk[1][0] : r0);   // keys 8C+4,5
        wa[3] = (int)(e ? dk[1][1] : r1);   // keys 8C+6,7
        short8 ap = *(short8*)&wa;

        // ---- PV + row-sum (ones); V-side reads the SAME chunk C(quad) ----
        const __hip_bfloat16* Vc = Vsb + cur * 2048;
        __builtin_amdgcn_s_setprio(1);
        lacc = __builtin_amdgcn_mfma_f32_16x16x32_bf16(ap, ones, lacc, 0, 0, 0);
#pragma unroll
        for (int tt = 0; tt < 4; tt++) {
            const int d = tt * 16 + m16;
            short8 bv = *(const short8*)&Vc[d * 32 + vsl];
            o[tt] = __builtin_amdgcn_mfma_f32_16x16x32_bf16(ap, bv, o[tt], 0, 0, 0);
        }
        __builtin_amdgcn_s_setprio(0);
        __syncthreads();  // drains DMA (vmcnt) + barrier: next buffer ready, cur reusable
    }

    // ---- merge the two key-halves (fixed-max => partials are additive) ----
    // Team 1 parks (o, lacc) in LDS (stride 21 floats: odd, bank-conflict-lean);
    // team 0 adds, normalizes, writes ctx.
    float* xch = (float*)smem;
    const int xi = (tw * 64 + lane) * 21;
    if (team == 1) {
#pragma unroll
        for (int tt = 0; tt < 4; tt++)
#pragma unroll
            for (int r = 0; r < 4; r++) xch[xi + tt * 4 + r] = o[tt][r];
#pragma unroll
        for (int r = 0; r < 4; r++) xch[xi + 16 + r] = lacc[r];
    }
    __syncthreads();
    if (team == 0) {
        float li[4];
#pragma unroll
        for (int r = 0; r < 4; r++) li[r] = 1.0f / (lacc[r] + xch[xi + 16 + r]);
#pragma unroll
        for (int tt = 0; tt < 4; tt++)
#pragma unroll
            for (int r = 0; r < 4; r++) {
                int srow = qbase + quad * 4 + r;
                int d = tt * 16 + m16;
                float v = (o[tt][r] + xch[xi + tt * 4 + r]) * li[r];
                ctx[((size_t)b * S_LEN + srow) * DMODEL + h * HD + d] = __float2bfloat16(v);
            }
    }
}

extern "C" void kernel_launch(void* const* d_in, const int* in_sizes, int n_in,
                              void* d_out, int out_size, void* d_ws, size_t ws_size,
                              hipStream_t stream) {
    (void)in_sizes; (void)n_in; (void)out_size; (void)ws_size;
    const float* hidden = (const float*)d_in[0];  // [2,2048,1024] fp32
    const float* mask   = (const float*)d_in[1];  // [2,1,1,2048] fp32
    const float* Wqkv   = (const float*)d_in[2];  // [1024,3072] fp32 [in,out]
    const float* bqkv   = (const float*)d_in[3];  // [3072] fp32
    const float* Wproj  = (const float*)d_in[4];  // [1024,1024] fp32 [in,out]
    const float* bproj  = (const float*)d_in[5];  // [1024] fp32
    float* out = (float*)d_out;                   // fp32 output

    // ---- workspace layout (peak 19M bf16 elems = 38 MB) ----
    __hip_bfloat16* ws = (__hip_bfloat16*)d_ws;
    const size_t Q4 = 4u * 1024 * 1024;
    __hip_bfloat16* Qp      = ws;
    __hip_bfloat16* Kp      = ws + 1 * Q4;
    __hip_bfloat16* Vt      = ws + 2 * Q4;
    __hip_bfloat16* hid_bf  = ws + 3 * Q4;
    __hip_bfloat16* ctx     = ws + 3 * Q4;   // overlaps hid_bf (disjoint lifetime)
    __hip_bfloat16* Wqkv_t  = ws + 4 * Q4;
    __hip_bfloat16* Wproj_t = ws + 4 * Q4;   // overlaps Wqkv_t (disjoint lifetime)

    cvt_kernel<<<dim3(4 * 1024 * 1024 / 2048), 256, 0, stream>>>(hidden, hid_bf);
    transpose_kernel<<<dim3(3072 / 32, 1024 / 32), dim3(32, 8), 0, stream>>>(Wqkv, Wqkv_t, 1024, 3072);

    // QKV projection + scatter: M=4096, N=3072, K=1024
    gemm128<<<dim3(3072 / 128, 4096 / 128), 256, 0, stream>>>(
        hid_bf, Wqkv_t, bqkv, nullptr, Qp, Kp, Vt, BATCH * S_LEN, 3 * DMODEL, DMODEL, 1);

    transpose_kernel<<<dim3(1024 / 32, 1024 / 32), dim3(32, 8), 0, stream>>>(Wproj, Wproj_t, 1024, 1024);

    attn_kernel<<<dim3(BATCH * NH, S_LEN / 64), 512, 0, stream>>>(Qp, Kp, Vt, mask, ctx);

    // output projection: M=4096, N=1024, K=1024 -> fp32 out
    gemm128<<<dim3(1024 / 128, 4096 / 128), 256, 0, stream>>>(
        ctx, Wproj_t, bproj, out, nullptr, nullptr, nullptr, BATCH * S_LEN, DMODEL, DMODEL, 0);
}